// Round 2
// baseline (2356.259 us; speedup 1.0000x reference)
//
#include <hip/hip_runtime.h>
#include <math.h>

#define T_STEPS 8
#define N_NODES 20000
#define F_IN    128
#define H_DIM   256
#define E_EDGES 320000

typedef __attribute__((ext_vector_type(8))) short short8;
typedef __attribute__((ext_vector_type(4))) float f32x4;

__device__ __forceinline__ float bf2f(unsigned short u) {
    return __uint_as_float(((unsigned)u) << 16);
}
// split v = hi + lo with hi = truncate-to-bf16(v); lo captures remainder to ~2^-16 rel
__device__ __forceinline__ void split2(float v, unsigned short& h, unsigned short& l) {
    unsigned vi = __float_as_uint(v);
    h = (unsigned short)(vi >> 16);
    float hf = __uint_as_float(vi & 0xffff0000u);
    l = (unsigned short)(__float_as_uint(v - hf) >> 16);
}

// ---------------- CSR build ----------------

__global__ void count_kernel(const int* __restrict__ dst, int* __restrict__ counts, int E) {
    int e = blockIdx.x * blockDim.x + threadIdx.x;
    if (e < E) atomicAdd(&counts[dst[e]], 1);
}

__global__ void scan_kernel(const int* __restrict__ counts, int* __restrict__ row_ptr,
                            int* __restrict__ cursors, int n) {
    __shared__ int buf[1024];
    __shared__ int carry_s;
    int tid = threadIdx.x;
    if (tid == 0) carry_s = 0;
    __syncthreads();
    for (int base = 0; base < n; base += 1024) {
        int i = base + tid;
        int v = (i < n) ? counts[i] : 0;
        buf[tid] = v;
        __syncthreads();
        for (int off = 1; off < 1024; off <<= 1) {
            int t = (tid >= off) ? buf[tid - off] : 0;
            __syncthreads();
            buf[tid] += t;
            __syncthreads();
        }
        int incl = buf[tid];
        int carry = carry_s;
        if (i < n) {
            int ex = carry + incl - v;
            row_ptr[i] = ex;
            cursors[i] = ex;
        }
        __syncthreads();
        if (tid == 1023) carry_s = carry + incl;
        __syncthreads();
    }
    if (tid == 0) row_ptr[n] = carry_s;
}

__global__ void fill_kernel(const int* __restrict__ src, const int* __restrict__ dst,
                            int* __restrict__ cursors, int* __restrict__ col, int E) {
    int e = blockIdx.x * blockDim.x + threadIdx.x;
    if (e < E) {
        int d = dst[e];
        int p = atomicAdd(&cursors[d], 1);
        col[p] = src[e];
    }
}

// ---------------- weight fp32 -> bf16 hi/lo ----------------

__global__ void cvt_w_kernel(const float* __restrict__ w, unsigned short* __restrict__ h,
                             unsigned short* __restrict__ l, int n) {
    int i = blockIdx.x * blockDim.x + threadIdx.x;
    if (i < n) {
        unsigned short hh, ll;
        split2(w[i], hh, ll);
        h[i] = hh; l[i] = ll;
    }
}

// ---------------- gather: agg[i,:] = sum_{j in row i} s[col[j],:] ----------------
// state layout: [node][ h(256) | l(256) ] bf16. One wave per node; lanes 0..31
// accumulate hi-parts, lanes 32..63 lo-parts; combine via shfl_xor.

__global__ __launch_bounds__(256) void gather_kernel(
        const unsigned short* __restrict__ shl, const int* __restrict__ row_ptr,
        const int* __restrict__ col, unsigned short* __restrict__ agg, int n) {
    int wv = threadIdx.x >> 6, lane = threadIdx.x & 63;
    int node = blockIdx.x * 4 + wv;
    if (node >= n) return;
    int beg = row_ptr[node], end = row_ptr[node + 1];
    float a[8] = {0.f, 0.f, 0.f, 0.f, 0.f, 0.f, 0.f, 0.f};
    int j = beg;
    for (; j + 1 < end; j += 2) {
        int c0 = col[j], c1 = col[j + 1];
        short8 v0 = *(const short8*)(shl + (size_t)c0 * 512 + lane * 8);
        short8 v1 = *(const short8*)(shl + (size_t)c1 * 512 + lane * 8);
        #pragma unroll
        for (int i = 0; i < 8; ++i)
            a[i] += bf2f((unsigned short)v0[i]) + bf2f((unsigned short)v1[i]);
    }
    if (j < end) {
        short8 v = *(const short8*)(shl + (size_t)col[j] * 512 + lane * 8);
        #pragma unroll
        for (int i = 0; i < 8; ++i) a[i] += bf2f((unsigned short)v[i]);
    }
    #pragma unroll
    for (int i = 0; i < 8; ++i) a[i] += __shfl_xor(a[i], 32, 64);
    if (lane < 32) {
        short8 hv, lv;
        #pragma unroll
        for (int i = 0; i < 8; ++i) {
            unsigned short h, l;
            split2(a[i], h, l);
            hv[i] = (short)h; lv[i] = (short)l;
        }
        *(short8*)(agg + (size_t)node * 512 + lane * 8) = hv;
        *(short8*)(agg + (size_t)node * 512 + 256 + lane * 8) = lv;
    }
}

// ---------------- MFMA update ----------------
// C[m,n] = sum_k A[m,k] W[n,k]; A from (fp32 X | hi/lo state) + optional agg part.
// s_out = leak*tanh(C) + (1-leak)*s_old.  128x128 block tile, 4 waves of 64x64,
// mfma_f32_16x16x32_bf16, 3-pass hi/lo split.

#define LDA 40   // bf16 stride of staged tiles: 20-word row stride -> uniform bank load

__global__ __launch_bounds__(256) void update_mfma(
        const float* __restrict__ A1f, const unsigned short* __restrict__ A1hl, int K1,
        const unsigned short* __restrict__ A2hl,
        const unsigned short* __restrict__ Bh1, const unsigned short* __restrict__ Bl1,
        const unsigned short* __restrict__ Bh2, const unsigned short* __restrict__ Bl2,
        const unsigned short* __restrict__ Sold,
        unsigned short* __restrict__ Southl, float* __restrict__ Soutf,
        int M, const float* __restrict__ leak_ptr) {
    __shared__ __align__(16) char smem[40960];
    unsigned short* Ah = (unsigned short*)smem;
    unsigned short* Al = Ah + 128 * LDA;
    unsigned short* Bh = Al + 128 * LDA;
    unsigned short* Bl = Bh + 128 * LDA;

    const int tid = threadIdx.x;
    const int lane = tid & 63, w = tid >> 6;
    const int m0 = blockIdx.x * 128, n0 = blockIdx.y * 128;
    const int fr = lane & 15, fq = lane >> 4;
    const int wn = (w & 1) * 64, wm = (w >> 1) * 64;

    f32x4 acc[4][4];
    #pragma unroll
    for (int i = 0; i < 4; ++i)
        #pragma unroll
        for (int jn = 0; jn < 4; ++jn)
            acc[i][jn] = (f32x4){0.f, 0.f, 0.f, 0.f};

    #pragma unroll 1
    for (int part = 0; part < 2; ++part) {
        const float* Af; const unsigned short* Ahl; int Kp, astr;
        const unsigned short *Bhp, *Blp;
        if (part == 0) {
            Af = A1f; Ahl = A1hl; Kp = K1; astr = A1hl ? 2 * K1 : K1;
            Bhp = Bh1; Blp = Bl1;
        } else {
            if (!A2hl) break;
            Af = nullptr; Ahl = A2hl; Kp = H_DIM; astr = 2 * H_DIM;
            Bhp = Bh2; Blp = Bl2;
        }
        #pragma unroll 1
        for (int kk = 0; kk < Kp; kk += 32) {
            if (Af) {
                // fp32 source: convert to hi/lo while staging
                #pragma unroll
                for (int r = 0; r < 4; ++r) {
                    int c = tid + r * 256;
                    int row = c >> 3, q = c & 7;
                    float4 v = make_float4(0.f, 0.f, 0.f, 0.f);
                    if (m0 + row < M)
                        v = *(const float4*)(Af + (size_t)(m0 + row) * astr + kk + q * 4);
                    unsigned short h0, h1, h2, h3, l0, l1, l2, l3;
                    split2(v.x, h0, l0); split2(v.y, h1, l1);
                    split2(v.z, h2, l2); split2(v.w, h3, l3);
                    *(ushort4*)(Ah + row * LDA + q * 4) = make_ushort4(h0, h1, h2, h3);
                    *(ushort4*)(Al + row * LDA + q * 4) = make_ushort4(l0, l1, l2, l3);
                }
            } else {
                #pragma unroll
                for (int r = 0; r < 2; ++r) {
                    int c = tid + r * 256;
                    int row = c >> 2, q = c & 3;
                    short8 vh = {0,0,0,0,0,0,0,0}, vl = {0,0,0,0,0,0,0,0};
                    if (m0 + row < M) {
                        const unsigned short* p = Ahl + (size_t)(m0 + row) * astr + kk + q * 8;
                        vh = *(const short8*)p;
                        vl = *(const short8*)(p + Kp);
                    }
                    *(short8*)(Ah + row * LDA + q * 8) = vh;
                    *(short8*)(Al + row * LDA + q * 8) = vl;
                }
            }
            #pragma unroll
            for (int r = 0; r < 2; ++r) {
                int c = tid + r * 256;
                int row = c >> 2, q = c & 3;
                size_t boff = (size_t)(n0 + row) * Kp + kk + q * 8;
                *(short8*)(Bh + row * LDA + q * 8) = *(const short8*)(Bhp + boff);
                *(short8*)(Bl + row * LDA + q * 8) = *(const short8*)(Blp + boff);
            }
            __syncthreads();
            short8 ahf[4], alf[4], bhf[4], blf[4];
            #pragma unroll
            for (int i = 0; i < 4; ++i) {
                int ao = (wm + i * 16 + fr) * LDA + fq * 8;
                int bo = (wn + i * 16 + fr) * LDA + fq * 8;
                ahf[i] = *(const short8*)(Ah + ao);
                alf[i] = *(const short8*)(Al + ao);
                bhf[i] = *(const short8*)(Bh + bo);
                blf[i] = *(const short8*)(Bl + bo);
            }
            #pragma unroll
            for (int i = 0; i < 4; ++i)
                #pragma unroll
                for (int jn = 0; jn < 4; ++jn) {
                    f32x4 c = acc[i][jn];
                    c = __builtin_amdgcn_mfma_f32_16x16x32_bf16(ahf[i], bhf[jn], c, 0, 0, 0);
                    c = __builtin_amdgcn_mfma_f32_16x16x32_bf16(alf[i], bhf[jn], c, 0, 0, 0);
                    c = __builtin_amdgcn_mfma_f32_16x16x32_bf16(ahf[i], blf[jn], c, 0, 0, 0);
                    acc[i][jn] = c;
                }
            __syncthreads();
        }
    }

    // epilogue: route acc through LDS for vectorized global I/O
    const float leak = leak_ptr[0], il = 1.0f - leak;
    float* ep = (float*)smem;
    const int LE = 133;
    #pragma unroll 1
    for (int p = 0; p < 2; ++p) {
        __syncthreads();
        #pragma unroll
        for (int mi = 0; mi < 2; ++mi) {
            #pragma unroll
            for (int nt = 0; nt < 4; ++nt) {
                f32x4 a = acc[2 * p + mi][nt];
                int row = (w >> 1) * 32 + mi * 16 + fq * 4;
                int cx = wn + nt * 16 + fr;
                ep[(row + 0) * LE + cx] = a[0];
                ep[(row + 1) * LE + cx] = a[1];
                ep[(row + 2) * LE + cx] = a[2];
                ep[(row + 3) * LE + cx] = a[3];
            }
        }
        __syncthreads();
        int lr = tid & 63, ch = tid >> 6;
        int mloc = (lr < 32) ? (p * 32 + lr) : (64 + p * 32 + (lr - 32));
        int m = m0 + mloc;
        if (m < M) {
            int gc = n0 + ch * 32;
            const unsigned short* op = Sold + (size_t)m * 512 + gc;
            unsigned short* dp = Southl + (size_t)m * 512 + gc;
            #pragma unroll
            for (int q = 0; q < 4; ++q) {
                short8 ohv = *(const short8*)(op + q * 8);
                short8 olv = *(const short8*)(op + 256 + q * 8);
                short8 hv, lv;
                float fo[8];
                #pragma unroll
                for (int jj = 0; jj < 8; ++jj) {
                    float pre = ep[lr * LE + ch * 32 + q * 8 + jj];
                    float e = __expf(2.0f * pre);
                    float th = 1.0f - 2.0f / (e + 1.0f);
                    float old = bf2f((unsigned short)ohv[jj]) + bf2f((unsigned short)olv[jj]);
                    float sn = leak * th + il * old;
                    fo[jj] = sn;
                    unsigned short hh, ll;
                    split2(sn, hh, ll);
                    hv[jj] = (short)hh; lv[jj] = (short)ll;
                }
                *(short8*)(dp + q * 8) = hv;
                *(short8*)(dp + 256 + q * 8) = lv;
                if (Soutf) {
                    float* o = Soutf + (size_t)m * H_DIM + gc + q * 8;
                    *(float4*)o = make_float4(fo[0], fo[1], fo[2], fo[3]);
                    *(float4*)(o + 4) = make_float4(fo[4], fo[5], fo[6], fo[7]);
                }
            }
        }
    }
}

// ---------------- launch ----------------

extern "C" void kernel_launch(void* const* d_in, const int* in_sizes, int n_in,
                              void* d_out, int out_size, void* d_ws, size_t ws_size,
                              hipStream_t stream) {
    const float* x        = (const float*)d_in[0];
    const int*   edge     = (const int*)d_in[1];
    const float* w_in0    = (const float*)d_in[2];
    const float* w_rec0   = (const float*)d_in[3];
    const float* w_in1    = (const float*)d_in[4];
    const float* w_rec1   = (const float*)d_in[5];
    const float* leak_ptr = (const float*)d_in[6];

    const int* src = edge;
    const int* dst = edge + E_EDGES;
    float* out = (float*)d_out;

    char* ws = (char*)d_ws;
    size_t off = 0;
    auto alloc = [&](size_t bytes) -> char* {
        char* p = ws + off;
        off += (bytes + 255) & ~(size_t)255;
        return p;
    };
    const size_t state_bytes = (size_t)N_NODES * 512 * sizeof(unsigned short);
    unsigned short* s0hl  = (unsigned short*)alloc(state_bytes);
    unsigned short* s1hl  = (unsigned short*)alloc(state_bytes);
    unsigned short* agghl = (unsigned short*)alloc(state_bytes);
    unsigned short* w0h  = (unsigned short*)alloc(256 * 128 * 2);
    unsigned short* w0l  = (unsigned short*)alloc(256 * 128 * 2);
    unsigned short* wr0h = (unsigned short*)alloc(256 * 256 * 2);
    unsigned short* wr0l = (unsigned short*)alloc(256 * 256 * 2);
    unsigned short* w1h  = (unsigned short*)alloc(256 * 256 * 2);
    unsigned short* w1l  = (unsigned short*)alloc(256 * 256 * 2);
    unsigned short* wr1h = (unsigned short*)alloc(256 * 256 * 2);
    unsigned short* wr1l = (unsigned short*)alloc(256 * 256 * 2);
    int* row_ptr = (int*)alloc((N_NODES + 1) * sizeof(int));
    int* cursors = (int*)alloc(N_NODES * sizeof(int));
    int* counts  = (int*)alloc(N_NODES * sizeof(int));
    int* col     = (int*)alloc((size_t)E_EDGES * sizeof(int));

    hipMemsetAsync(s0hl, 0, state_bytes, stream);
    hipMemsetAsync(s1hl, 0, state_bytes, stream);
    hipMemsetAsync(counts, 0, N_NODES * sizeof(int), stream);

    cvt_w_kernel<<<(256 * 128 + 255) / 256, 256, 0, stream>>>(w_in0, w0h, w0l, 256 * 128);
    cvt_w_kernel<<<(256 * 256 + 255) / 256, 256, 0, stream>>>(w_rec0, wr0h, wr0l, 256 * 256);
    cvt_w_kernel<<<(256 * 256 + 255) / 256, 256, 0, stream>>>(w_in1, w1h, w1l, 256 * 256);
    cvt_w_kernel<<<(256 * 256 + 255) / 256, 256, 0, stream>>>(w_rec1, wr1h, wr1l, 256 * 256);

    count_kernel<<<(E_EDGES + 255) / 256, 256, 0, stream>>>(dst, counts, E_EDGES);
    scan_kernel<<<1, 1024, 0, stream>>>(counts, row_ptr, cursors, N_NODES);
    fill_kernel<<<(E_EDGES + 255) / 256, 256, 0, stream>>>(src, dst, cursors, col, E_EDGES);

    dim3 ggrid((N_NODES + 3) / 4);
    dim3 ugrid((N_NODES + 127) / 128, H_DIM / 128);

    for (int t = 0; t < T_STEPS; ++t) {
        const float* xt = x + (size_t)t * N_NODES * F_IN;
        if (t == 0) {
            update_mfma<<<ugrid, 256, 0, stream>>>(
                xt, nullptr, F_IN, nullptr,
                w0h, w0l, nullptr, nullptr,
                s0hl, s0hl, nullptr, N_NODES, leak_ptr);
            update_mfma<<<ugrid, 256, 0, stream>>>(
                nullptr, s0hl, H_DIM, nullptr,
                w1h, w1l, nullptr, nullptr,
                s1hl, s1hl, out, N_NODES, leak_ptr);
        } else {
            gather_kernel<<<ggrid, 256, 0, stream>>>(s0hl, row_ptr, col, agghl, N_NODES);
            update_mfma<<<ugrid, 256, 0, stream>>>(
                xt, nullptr, F_IN, agghl,
                w0h, w0l, wr0h, wr0l,
                s0hl, s0hl, nullptr, N_NODES, leak_ptr);
            gather_kernel<<<ggrid, 256, 0, stream>>>(s1hl, row_ptr, col, agghl, N_NODES);
            update_mfma<<<ugrid, 256, 0, stream>>>(
                nullptr, s0hl, H_DIM, agghl,
                w1h, w1l, wr1h, wr1l,
                s1hl, s1hl, out, N_NODES, leak_ptr);
        }
    }
}

// Round 3
// 2306.744 us; speedup vs baseline: 1.0215x; 1.0215x over previous
//
#include <hip/hip_runtime.h>
#include <math.h>

#define T_STEPS 8
#define N_NODES 20000
#define F_IN    128
#define H_DIM   256
#define E_EDGES 320000

typedef __attribute__((ext_vector_type(8))) short short8;
typedef __attribute__((ext_vector_type(4))) float f32x4;

__device__ __forceinline__ void split2(float v, unsigned short& h, unsigned short& l) {
    unsigned vi = __float_as_uint(v);
    h = (unsigned short)(vi >> 16);
    float hf = __uint_as_float(vi & 0xffff0000u);
    l = (unsigned short)(__float_as_uint(v - hf) >> 16);
}

// ---------------- CSR build ----------------

__global__ void count_kernel(const int* __restrict__ dst, int* __restrict__ counts, int E) {
    int e = blockIdx.x * blockDim.x + threadIdx.x;
    if (e < E) atomicAdd(&counts[dst[e]], 1);
}

__global__ void scan_kernel(const int* __restrict__ counts, int* __restrict__ row_ptr,
                            int* __restrict__ cursors, int n) {
    __shared__ int buf[1024];
    __shared__ int carry_s;
    int tid = threadIdx.x;
    if (tid == 0) carry_s = 0;
    __syncthreads();
    for (int base = 0; base < n; base += 1024) {
        int i = base + tid;
        int v = (i < n) ? counts[i] : 0;
        buf[tid] = v;
        __syncthreads();
        for (int off = 1; off < 1024; off <<= 1) {
            int t = (tid >= off) ? buf[tid - off] : 0;
            __syncthreads();
            buf[tid] += t;
            __syncthreads();
        }
        int incl = buf[tid];
        int carry = carry_s;
        if (i < n) {
            int ex = carry + incl - v;
            row_ptr[i] = ex;
            cursors[i] = ex;
        }
        __syncthreads();
        if (tid == 1023) carry_s = carry + incl;
        __syncthreads();
    }
    if (tid == 0) row_ptr[n] = carry_s;
}

__global__ void fill_kernel(const int* __restrict__ src, const int* __restrict__ dst,
                            int* __restrict__ cursors, int* __restrict__ col, int E) {
    int e = blockIdx.x * blockDim.x + threadIdx.x;
    if (e < E) {
        int d = dst[e];
        int p = atomicAdd(&cursors[d], 1);
        col[p] = src[e];
    }
}

// ---------------- weight fp32 -> bf16 hi/lo ----------------

__global__ void cvt_w_kernel(const float* __restrict__ w, unsigned short* __restrict__ h,
                             unsigned short* __restrict__ l, int n) {
    int i = blockIdx.x * blockDim.x + threadIdx.x;
    if (i < n) {
        unsigned short hh, ll;
        split2(w[i], hh, ll);
        h[i] = hh; l[i] = ll;
    }
}

// ---------------- gather: agg[i,:] = sum_{j in row i} s[col[j],:] ----------------
// one wave per node; lane holds float4 (64*4 = 256 = H); fully coalesced 1KB rows

__global__ __launch_bounds__(256) void gather_kernel(
        const float* __restrict__ s, const int* __restrict__ row_ptr,
        const int* __restrict__ col, float* __restrict__ agg, int n) {
    int wv = threadIdx.x >> 6, lane = threadIdx.x & 63;
    int node = blockIdx.x * 4 + wv;
    if (node >= n) return;
    int beg = row_ptr[node], end = row_ptr[node + 1];
    const float4* s4 = (const float4*)s;
    float ax = 0.f, ay = 0.f, az = 0.f, aw = 0.f;
    float bx = 0.f, by = 0.f, bz = 0.f, bw = 0.f;
    int j = beg;
    for (; j + 1 < end; j += 2) {
        int c0 = col[j], c1 = col[j + 1];
        float4 v0 = s4[(size_t)c0 * 64 + lane];
        float4 v1 = s4[(size_t)c1 * 64 + lane];
        ax += v0.x; ay += v0.y; az += v0.z; aw += v0.w;
        bx += v1.x; by += v1.y; bz += v1.z; bw += v1.w;
    }
    if (j < end) {
        int c = col[j];
        float4 v = s4[(size_t)c * 64 + lane];
        ax += v.x; ay += v.y; az += v.z; aw += v.w;
    }
    float4 o;
    o.x = ax + bx; o.y = ay + by; o.z = az + bz; o.w = aw + bw;
    ((float4*)agg)[(size_t)node * 64 + lane] = o;
}

// ---------------- MFMA update ----------------
// C[m,n] = sum_k A1[m,k] W1[n,k] (+ sum_k A2[m,k] W2[n,k])
// s_out = leak*tanh(C) + (1-leak)*s_old.  All A/state fp32; weights bf16 hi/lo.
// 128x128 block tile, 4 waves of 64x64, mfma_f32_16x16x32_bf16, 3-pass split.

#define LDA 40   // bf16 stride of staged tiles (20 dwords -> conflict-light)

__global__ __launch_bounds__(256) void update_mfma(
        const float* __restrict__ A1, int K1,
        const float* __restrict__ A2,
        const unsigned short* __restrict__ Bh1, const unsigned short* __restrict__ Bl1,
        const unsigned short* __restrict__ Bh2, const unsigned short* __restrict__ Bl2,
        const float* __restrict__ s_old, float* __restrict__ s_out,
        int M, const float* __restrict__ leak_ptr) {
    __shared__ __align__(16) char smem[40960];
    unsigned short* Ah = (unsigned short*)smem;
    unsigned short* Al = Ah + 128 * LDA;
    unsigned short* Bh = Al + 128 * LDA;
    unsigned short* Bl = Bh + 128 * LDA;

    const int tid = threadIdx.x;
    const int lane = tid & 63, w = tid >> 6;
    const int m0 = blockIdx.x * 128, n0 = blockIdx.y * 128;
    const int fr = lane & 15, fq = lane >> 4;
    const int wn = (w & 1) * 64;

    f32x4 acc[4][4];
    #pragma unroll
    for (int i = 0; i < 4; ++i)
        #pragma unroll
        for (int jn = 0; jn < 4; ++jn)
            acc[i][jn] = (f32x4){0.f, 0.f, 0.f, 0.f};

    #pragma unroll 1
    for (int part = 0; part < 2; ++part) {
        const float* Af; int Kp;
        const unsigned short *Bhp, *Blp;
        if (part == 0) { Af = A1; Kp = K1; Bhp = Bh1; Blp = Bl1; }
        else {
            if (!A2) break;
            Af = A2; Kp = H_DIM; Bhp = Bh2; Blp = Bl2;
        }
        #pragma unroll 1
        for (int kk = 0; kk < Kp; kk += 32) {
            // A tile: 128 rows x 32 floats, convert fp32 -> hi/lo while staging
            #pragma unroll
            for (int r = 0; r < 4; ++r) {
                int c = tid + r * 256;
                int row = c >> 3, q = c & 7;
                float4 v = make_float4(0.f, 0.f, 0.f, 0.f);
                if (m0 + row < M)
                    v = *(const float4*)(Af + (size_t)(m0 + row) * Kp + kk + q * 4);
                unsigned short h0, h1, h2, h3, l0, l1, l2, l3;
                split2(v.x, h0, l0); split2(v.y, h1, l1);
                split2(v.z, h2, l2); split2(v.w, h3, l3);
                *(ushort4*)(Ah + row * LDA + q * 4) = make_ushort4(h0, h1, h2, h3);
                *(ushort4*)(Al + row * LDA + q * 4) = make_ushort4(l0, l1, l2, l3);
            }
            // B tile: 128 weight rows x 32 cols (bf16 hi/lo, pre-split)
            #pragma unroll
            for (int r = 0; r < 2; ++r) {
                int c = tid + r * 256;
                int row = c >> 2, q = c & 3;
                size_t boff = (size_t)(n0 + row) * Kp + kk + q * 8;
                *(short8*)(Bh + row * LDA + q * 8) = *(const short8*)(Bhp + boff);
                *(short8*)(Bl + row * LDA + q * 8) = *(const short8*)(Blp + boff);
            }
            __syncthreads();
            short8 ahf[4], alf[4], bhf[4], blf[4];
            #pragma unroll
            for (int i = 0; i < 4; ++i) {
                int ao = ((w >> 1) * 64 + i * 16 + fr) * LDA + fq * 8;
                int bo = (wn + i * 16 + fr) * LDA + fq * 8;
                ahf[i] = *(const short8*)(Ah + ao);
                alf[i] = *(const short8*)(Al + ao);
                bhf[i] = *(const short8*)(Bh + bo);
                blf[i] = *(const short8*)(Bl + bo);
            }
            #pragma unroll
            for (int i = 0; i < 4; ++i)
                #pragma unroll
                for (int jn = 0; jn < 4; ++jn) {
                    f32x4 c = acc[i][jn];
                    c = __builtin_amdgcn_mfma_f32_16x16x32_bf16(ahf[i], bhf[jn], c, 0, 0, 0);
                    c = __builtin_amdgcn_mfma_f32_16x16x32_bf16(alf[i], bhf[jn], c, 0, 0, 0);
                    c = __builtin_amdgcn_mfma_f32_16x16x32_bf16(ahf[i], blf[jn], c, 0, 0, 0);
                    acc[i][jn] = c;
                }
            __syncthreads();
        }
    }

    // epilogue: acc -> LDS -> coalesced fp32 global (wave writes 2 rows x 512B)
    const float leak = leak_ptr[0], il = 1.0f - leak;
    float* ep = (float*)smem;
    const int LE = 133;
    #pragma unroll 1
    for (int p = 0; p < 2; ++p) {
        __syncthreads();
        #pragma unroll
        for (int mi = 0; mi < 2; ++mi) {
            #pragma unroll
            for (int nt = 0; nt < 4; ++nt) {
                f32x4 a = acc[2 * p + mi][nt];
                int row = (w >> 1) * 32 + mi * 16 + fq * 4;
                int cx = wn + nt * 16 + fr;
                ep[(row + 0) * LE + cx] = a[0];
                ep[(row + 1) * LE + cx] = a[1];
                ep[(row + 2) * LE + cx] = a[2];
                ep[(row + 3) * LE + cx] = a[3];
            }
        }
        __syncthreads();
        #pragma unroll
        for (int it = 0; it < 8; ++it) {
            int g = it * 256 + tid;
            int er = g >> 5;          // 0..63 (ep row)
            int c4 = g & 31;          // float4 chunk within 128 cols
            int mloc = (er < 32) ? (p * 32 + er) : (64 + p * 32 + (er - 32));
            int m = m0 + mloc;
            if (m < M) {
                float4 pre = *(const float4*)&ep[er * LE + c4 * 4];
                const float* op = s_old + (size_t)m * H_DIM + n0 + c4 * 4;
                float4 old = *(const float4*)op;
                float4 o;
                {
                    float e0 = __expf(2.0f * pre.x), e1 = __expf(2.0f * pre.y);
                    float e2 = __expf(2.0f * pre.z), e3 = __expf(2.0f * pre.w);
                    o.x = leak * (1.0f - 2.0f / (e0 + 1.0f)) + il * old.x;
                    o.y = leak * (1.0f - 2.0f / (e1 + 1.0f)) + il * old.y;
                    o.z = leak * (1.0f - 2.0f / (e2 + 1.0f)) + il * old.z;
                    o.w = leak * (1.0f - 2.0f / (e3 + 1.0f)) + il * old.w;
                }
                *(float4*)(s_out + (size_t)m * H_DIM + n0 + c4 * 4) = o;
            }
        }
    }
}

// ---------------- launch ----------------

extern "C" void kernel_launch(void* const* d_in, const int* in_sizes, int n_in,
                              void* d_out, int out_size, void* d_ws, size_t ws_size,
                              hipStream_t stream) {
    const float* x        = (const float*)d_in[0];
    const int*   edge     = (const int*)d_in[1];
    const float* w_in0    = (const float*)d_in[2];
    const float* w_rec0   = (const float*)d_in[3];
    const float* w_in1    = (const float*)d_in[4];
    const float* w_rec1   = (const float*)d_in[5];
    const float* leak_ptr = (const float*)d_in[6];

    const int* src = edge;
    const int* dst = edge + E_EDGES;

    float* s1 = (float*)d_out;   // layer-1 state lives directly in d_out

    char* ws = (char*)d_ws;
    size_t off = 0;
    auto alloc = [&](size_t bytes) -> char* {
        char* p = ws + off;
        off += (bytes + 255) & ~(size_t)255;
        return p;
    };
    const size_t state_bytes = (size_t)N_NODES * H_DIM * sizeof(float);
    float* s0  = (float*)alloc(state_bytes);
    float* agg = (float*)alloc(state_bytes);
    unsigned short* w0h  = (unsigned short*)alloc(256 * 128 * 2);
    unsigned short* w0l  = (unsigned short*)alloc(256 * 128 * 2);
    unsigned short* wr0h = (unsigned short*)alloc(256 * 256 * 2);
    unsigned short* wr0l = (unsigned short*)alloc(256 * 256 * 2);
    unsigned short* w1h  = (unsigned short*)alloc(256 * 256 * 2);
    unsigned short* w1l  = (unsigned short*)alloc(256 * 256 * 2);
    unsigned short* wr1h = (unsigned short*)alloc(256 * 256 * 2);
    unsigned short* wr1l = (unsigned short*)alloc(256 * 256 * 2);
    int* row_ptr = (int*)alloc((N_NODES + 1) * sizeof(int));
    int* cursors = (int*)alloc(N_NODES * sizeof(int));
    int* counts  = (int*)alloc(N_NODES * sizeof(int));
    int* col     = (int*)alloc((size_t)E_EDGES * sizeof(int));

    hipMemsetAsync(s0, 0, state_bytes, stream);
    hipMemsetAsync(s1, 0, state_bytes, stream);
    hipMemsetAsync(counts, 0, N_NODES * sizeof(int), stream);

    cvt_w_kernel<<<(256 * 128 + 255) / 256, 256, 0, stream>>>(w_in0, w0h, w0l, 256 * 128);
    cvt_w_kernel<<<(256 * 256 + 255) / 256, 256, 0, stream>>>(w_rec0, wr0h, wr0l, 256 * 256);
    cvt_w_kernel<<<(256 * 256 + 255) / 256, 256, 0, stream>>>(w_in1, w1h, w1l, 256 * 256);
    cvt_w_kernel<<<(256 * 256 + 255) / 256, 256, 0, stream>>>(w_rec1, wr1h, wr1l, 256 * 256);

    count_kernel<<<(E_EDGES + 255) / 256, 256, 0, stream>>>(dst, counts, E_EDGES);
    scan_kernel<<<1, 1024, 0, stream>>>(counts, row_ptr, cursors, N_NODES);
    fill_kernel<<<(E_EDGES + 255) / 256, 256, 0, stream>>>(src, dst, cursors, col, E_EDGES);

    dim3 ggrid((N_NODES + 3) / 4);
    dim3 ugrid((N_NODES + 127) / 128, H_DIM / 128);

    for (int t = 0; t < T_STEPS; ++t) {
        const float* xt = x + (size_t)t * N_NODES * F_IN;
        if (t == 0) {
            update_mfma<<<ugrid, 256, 0, stream>>>(
                xt, F_IN, nullptr, w0h, w0l, nullptr, nullptr,
                s0, s0, N_NODES, leak_ptr);
            update_mfma<<<ugrid, 256, 0, stream>>>(
                s0, H_DIM, nullptr, w1h, w1l, nullptr, nullptr,
                s1, s1, N_NODES, leak_ptr);
        } else {
            gather_kernel<<<ggrid, 256, 0, stream>>>(s0, row_ptr, col, agg, N_NODES);
            update_mfma<<<ugrid, 256, 0, stream>>>(
                xt, F_IN, agg, w0h, w0l, wr0h, wr0l,
                s0, s0, N_NODES, leak_ptr);
            gather_kernel<<<ggrid, 256, 0, stream>>>(s1, row_ptr, col, agg, N_NODES);
            update_mfma<<<ugrid, 256, 0, stream>>>(
                s0, H_DIM, agg, w1h, w1l, wr1h, wr1l,
                s1, s1, N_NODES, leak_ptr);
        }
    }
}

// Round 4
// 2302.087 us; speedup vs baseline: 1.0235x; 1.0020x over previous
//
#include <hip/hip_runtime.h>
#include <math.h>

#define T_STEPS 8
#define N_NODES 20000
#define F_IN    128
#define H_DIM   256
#define E_EDGES 320000

typedef __attribute__((ext_vector_type(8))) short short8;
typedef __attribute__((ext_vector_type(4))) float f32x4;

__device__ __forceinline__ void split2(float v, unsigned short& h, unsigned short& l) {
    unsigned vi = __float_as_uint(v);
    h = (unsigned short)(vi >> 16);
    float hf = __uint_as_float(vi & 0xffff0000u);
    l = (unsigned short)(__float_as_uint(v - hf) >> 16);
}

// ---------------- CSR build ----------------

__global__ void count_kernel(const int* __restrict__ dst, int* __restrict__ counts, int E) {
    int e = blockIdx.x * blockDim.x + threadIdx.x;
    if (e < E) atomicAdd(&counts[dst[e]], 1);
}

__global__ void scan_kernel(const int* __restrict__ counts, int* __restrict__ row_ptr,
                            int* __restrict__ cursors, int n) {
    __shared__ int buf[1024];
    __shared__ int carry_s;
    int tid = threadIdx.x;
    if (tid == 0) carry_s = 0;
    __syncthreads();
    for (int base = 0; base < n; base += 1024) {
        int i = base + tid;
        int v = (i < n) ? counts[i] : 0;
        buf[tid] = v;
        __syncthreads();
        for (int off = 1; off < 1024; off <<= 1) {
            int t = (tid >= off) ? buf[tid - off] : 0;
            __syncthreads();
            buf[tid] += t;
            __syncthreads();
        }
        int incl = buf[tid];
        int carry = carry_s;
        if (i < n) {
            int ex = carry + incl - v;
            row_ptr[i] = ex;
            cursors[i] = ex;
        }
        __syncthreads();
        if (tid == 1023) carry_s = carry + incl;
        __syncthreads();
    }
    if (tid == 0) row_ptr[n] = carry_s;
}

__global__ void fill_kernel(const int* __restrict__ src, const int* __restrict__ dst,
                            int* __restrict__ cursors, int* __restrict__ col, int E) {
    int e = blockIdx.x * blockDim.x + threadIdx.x;
    if (e < E) {
        int d = dst[e];
        int p = atomicAdd(&cursors[d], 1);
        col[p] = src[e];
    }
}

// ---------------- weight fp32 -> bf16 hi/lo ----------------

__global__ void cvt_w_kernel(const float* __restrict__ w, unsigned short* __restrict__ h,
                             unsigned short* __restrict__ l, int n) {
    int i = blockIdx.x * blockDim.x + threadIdx.x;
    if (i < n) {
        unsigned short hh, ll;
        split2(w[i], hh, ll);
        h[i] = hh; l[i] = ll;
    }
}

// ---------------- gather: agg[i,:] = sum_{j in row i} s[col[j],:] ----------------

__global__ __launch_bounds__(256) void gather_kernel(
        const float* __restrict__ s, const int* __restrict__ row_ptr,
        const int* __restrict__ col, float* __restrict__ agg, int n) {
    int wv = threadIdx.x >> 6, lane = threadIdx.x & 63;
    int node = blockIdx.x * 4 + wv;
    if (node >= n) return;
    int beg = row_ptr[node], end = row_ptr[node + 1];
    const float4* s4 = (const float4*)s;
    float ax = 0.f, ay = 0.f, az = 0.f, aw = 0.f;
    float bx = 0.f, by = 0.f, bz = 0.f, bw = 0.f;
    int j = beg;
    for (; j + 1 < end; j += 2) {
        int c0 = col[j], c1 = col[j + 1];
        float4 v0 = s4[(size_t)c0 * 64 + lane];
        float4 v1 = s4[(size_t)c1 * 64 + lane];
        ax += v0.x; ay += v0.y; az += v0.z; aw += v0.w;
        bx += v1.x; by += v1.y; bz += v1.z; bw += v1.w;
    }
    if (j < end) {
        int c = col[j];
        float4 v = s4[(size_t)c * 64 + lane];
        ax += v.x; ay += v.y; az += v.z; aw += v.w;
    }
    float4 o;
    o.x = ax + bx; o.y = ay + by; o.z = az + bz; o.w = aw + bw;
    ((float4*)agg)[(size_t)node * 64 + lane] = o;
}

// ---------------- MFMA update ----------------
// C[m,n] = sum_k A1[m,k] W1[n,k] (+ sum_k A2[m,k] W2[n,k])
// s_out = leak*tanh(C) + (1-leak)*s_old.  States fp32; weights bf16 hi/lo.
// 128x128 block tile, 4 waves of 64x64, mfma_f32_16x16x32_bf16, 3-pass split.
// launch_bounds(256,2): allow ~256 VGPR/thread -- the ~150-reg inner loop must
// NOT spill (round-3 spilled at default budget: 314 MB of scratch writes).

#define LDA 40

__global__ __launch_bounds__(256, 2) void update_mfma(
        const float* __restrict__ A1, int K1,
        const float* __restrict__ A2,
        const unsigned short* __restrict__ Bh1, const unsigned short* __restrict__ Bl1,
        const unsigned short* __restrict__ Bh2, const unsigned short* __restrict__ Bl2,
        const float* __restrict__ s_old, float* __restrict__ s_out,
        int M, const float* __restrict__ leak_ptr) {
    __shared__ __align__(16) char smem[40960];
    unsigned short* Ah = (unsigned short*)smem;
    unsigned short* Al = Ah + 128 * LDA;
    unsigned short* Bh = Al + 128 * LDA;
    unsigned short* Bl = Bh + 128 * LDA;

    const int tid = threadIdx.x;
    const int lane = tid & 63, w = tid >> 6;
    const int m0 = blockIdx.x * 128, n0 = blockIdx.y * 128;
    const int fr = lane & 15, fq = lane >> 4;
    const int wn = (w & 1) * 64;

    f32x4 acc[4][4];
    #pragma unroll
    for (int i = 0; i < 4; ++i)
        #pragma unroll
        for (int jn = 0; jn < 4; ++jn)
            acc[i][jn] = (f32x4){0.f, 0.f, 0.f, 0.f};

    #pragma unroll 1
    for (int part = 0; part < 2; ++part) {
        const float* Af; int Kp;
        const unsigned short *Bhp, *Blp;
        if (part == 0) { Af = A1; Kp = K1; Bhp = Bh1; Blp = Bl1; }
        else {
            if (!A2) break;
            Af = A2; Kp = H_DIM; Bhp = Bh2; Blp = Bl2;
        }
        #pragma unroll 1
        for (int kk = 0; kk < Kp; kk += 32) {
            // A tile: 128 rows x 32 floats, fp32 -> hi/lo while staging
            #pragma unroll
            for (int r = 0; r < 4; ++r) {
                int c = tid + r * 256;
                int row = c >> 3, q = c & 7;
                float4 v = make_float4(0.f, 0.f, 0.f, 0.f);
                if (m0 + row < M)
                    v = *(const float4*)(Af + (size_t)(m0 + row) * Kp + kk + q * 4);
                unsigned short h0, h1, h2, h3, l0, l1, l2, l3;
                split2(v.x, h0, l0); split2(v.y, h1, l1);
                split2(v.z, h2, l2); split2(v.w, h3, l3);
                *(ushort4*)(Ah + row * LDA + q * 4) = make_ushort4(h0, h1, h2, h3);
                *(ushort4*)(Al + row * LDA + q * 4) = make_ushort4(l0, l1, l2, l3);
            }
            // B tile: 128 weight rows x 32 cols (bf16 hi/lo, pre-split)
            #pragma unroll
            for (int r = 0; r < 2; ++r) {
                int c = tid + r * 256;
                int row = c >> 2, q = c & 3;
                size_t boff = (size_t)(n0 + row) * Kp + kk + q * 8;
                *(short8*)(Bh + row * LDA + q * 8) = *(const short8*)(Bhp + boff);
                *(short8*)(Bl + row * LDA + q * 8) = *(const short8*)(Blp + boff);
            }
            __syncthreads();
            short8 ahf[4], alf[4], bhf[4], blf[4];
            #pragma unroll
            for (int i = 0; i < 4; ++i) {
                int ao = ((w >> 1) * 64 + i * 16 + fr) * LDA + fq * 8;
                int bo = (wn + i * 16 + fr) * LDA + fq * 8;
                ahf[i] = *(const short8*)(Ah + ao);
                alf[i] = *(const short8*)(Al + ao);
                bhf[i] = *(const short8*)(Bh + bo);
                blf[i] = *(const short8*)(Bl + bo);
            }
            #pragma unroll
            for (int i = 0; i < 4; ++i)
                #pragma unroll
                for (int jn = 0; jn < 4; ++jn) {
                    f32x4 c = acc[i][jn];
                    c = __builtin_amdgcn_mfma_f32_16x16x32_bf16(ahf[i], bhf[jn], c, 0, 0, 0);
                    c = __builtin_amdgcn_mfma_f32_16x16x32_bf16(alf[i], bhf[jn], c, 0, 0, 0);
                    c = __builtin_amdgcn_mfma_f32_16x16x32_bf16(ahf[i], blf[jn], c, 0, 0, 0);
                    acc[i][jn] = c;
                }
            __syncthreads();
        }
    }

    // epilogue: acc -> LDS -> coalesced fp32 global (wave writes 2 rows x 512B)
    const float leak = leak_ptr[0], il = 1.0f - leak;
    float* ep = (float*)smem;
    const int LE = 133;
    #pragma unroll 1
    for (int p = 0; p < 2; ++p) {
        __syncthreads();
        #pragma unroll
        for (int mi = 0; mi < 2; ++mi) {
            #pragma unroll
            for (int nt = 0; nt < 4; ++nt) {
                f32x4 a = acc[2 * p + mi][nt];
                int row = (w >> 1) * 32 + mi * 16 + fq * 4;
                int cx = wn + nt * 16 + fr;
                ep[(row + 0) * LE + cx] = a[0];
                ep[(row + 1) * LE + cx] = a[1];
                ep[(row + 2) * LE + cx] = a[2];
                ep[(row + 3) * LE + cx] = a[3];
            }
        }
        __syncthreads();
        #pragma unroll
        for (int it = 0; it < 8; ++it) {
            int g = it * 256 + tid;
            int er = g >> 5;
            int c4 = g & 31;
            int mloc = (er < 32) ? (p * 32 + er) : (64 + p * 32 + (er - 32));
            int m = m0 + mloc;
            if (m < M) {
                float4 pre = *(const float4*)&ep[er * LE + c4 * 4];
                const float* op = s_old + (size_t)m * H_DIM + n0 + c4 * 4;
                float4 old = *(const float4*)op;
                float4 o;
                float e0 = __expf(2.0f * pre.x), e1 = __expf(2.0f * pre.y);
                float e2 = __expf(2.0f * pre.z), e3 = __expf(2.0f * pre.w);
                o.x = leak * (1.0f - 2.0f / (e0 + 1.0f)) + il * old.x;
                o.y = leak * (1.0f - 2.0f / (e1 + 1.0f)) + il * old.y;
                o.z = leak * (1.0f - 2.0f / (e2 + 1.0f)) + il * old.z;
                o.w = leak * (1.0f - 2.0f / (e3 + 1.0f)) + il * old.w;
                *(float4*)(s_out + (size_t)m * H_DIM + n0 + c4 * 4) = o;
            }
        }
    }
}

// ---------------- launch ----------------

extern "C" void kernel_launch(void* const* d_in, const int* in_sizes, int n_in,
                              void* d_out, int out_size, void* d_ws, size_t ws_size,
                              hipStream_t stream) {
    const float* x        = (const float*)d_in[0];
    const int*   edge     = (const int*)d_in[1];
    const float* w_in0    = (const float*)d_in[2];
    const float* w_rec0   = (const float*)d_in[3];
    const float* w_in1    = (const float*)d_in[4];
    const float* w_rec1   = (const float*)d_in[5];
    const float* leak_ptr = (const float*)d_in[6];

    const int* src = edge;
    const int* dst = edge + E_EDGES;

    float* s1 = (float*)d_out;

    char* ws = (char*)d_ws;
    size_t off = 0;
    auto alloc = [&](size_t bytes) -> char* {
        char* p = ws + off;
        off += (bytes + 255) & ~(size_t)255;
        return p;
    };
    const size_t state_bytes = (size_t)N_NODES * H_DIM * sizeof(float);
    float* s0  = (float*)alloc(state_bytes);
    float* agg = (float*)alloc(state_bytes);
    unsigned short* w0h  = (unsigned short*)alloc(256 * 128 * 2);
    unsigned short* w0l  = (unsigned short*)alloc(256 * 128 * 2);
    unsigned short* wr0h = (unsigned short*)alloc(256 * 256 * 2);
    unsigned short* wr0l = (unsigned short*)alloc(256 * 256 * 2);
    unsigned short* w1h  = (unsigned short*)alloc(256 * 256 * 2);
    unsigned short* w1l  = (unsigned short*)alloc(256 * 256 * 2);
    unsigned short* wr1h = (unsigned short*)alloc(256 * 256 * 2);
    unsigned short* wr1l = (unsigned short*)alloc(256 * 256 * 2);
    int* row_ptr = (int*)alloc((N_NODES + 1) * sizeof(int));
    int* cursors = (int*)alloc(N_NODES * sizeof(int));
    int* counts  = (int*)alloc(N_NODES * sizeof(int));
    int* col     = (int*)alloc((size_t)E_EDGES * sizeof(int));

    hipMemsetAsync(s0, 0, state_bytes, stream);
    hipMemsetAsync(s1, 0, state_bytes, stream);
    hipMemsetAsync(counts, 0, N_NODES * sizeof(int), stream);

    cvt_w_kernel<<<(256 * 128 + 255) / 256, 256, 0, stream>>>(w_in0, w0h, w0l, 256 * 128);
    cvt_w_kernel<<<(256 * 256 + 255) / 256, 256, 0, stream>>>(w_rec0, wr0h, wr0l, 256 * 256);
    cvt_w_kernel<<<(256 * 256 + 255) / 256, 256, 0, stream>>>(w_in1, w1h, w1l, 256 * 256);
    cvt_w_kernel<<<(256 * 256 + 255) / 256, 256, 0, stream>>>(w_rec1, wr1h, wr1l, 256 * 256);

    count_kernel<<<(E_EDGES + 255) / 256, 256, 0, stream>>>(dst, counts, E_EDGES);
    scan_kernel<<<1, 1024, 0, stream>>>(counts, row_ptr, cursors, N_NODES);
    fill_kernel<<<(E_EDGES + 255) / 256, 256, 0, stream>>>(src, dst, cursors, col, E_EDGES);

    dim3 ggrid((N_NODES + 3) / 4);
    dim3 ugrid((N_NODES + 127) / 128, H_DIM / 128);

    for (int t = 0; t < T_STEPS; ++t) {
        const float* xt = x + (size_t)t * N_NODES * F_IN;
        if (t == 0) {
            update_mfma<<<ugrid, 256, 0, stream>>>(
                xt, F_IN, nullptr, w0h, w0l, nullptr, nullptr,
                s0, s0, N_NODES, leak_ptr);
            update_mfma<<<ugrid, 256, 0, stream>>>(
                s0, H_DIM, nullptr, w1h, w1l, nullptr, nullptr,
                s1, s1, N_NODES, leak_ptr);
        } else {
            gather_kernel<<<ggrid, 256, 0, stream>>>(s0, row_ptr, col, agg, N_NODES);
            update_mfma<<<ugrid, 256, 0, stream>>>(
                xt, F_IN, agg, w0h, w0l, wr0h, wr0l,
                s0, s0, N_NODES, leak_ptr);
            gather_kernel<<<ggrid, 256, 0, stream>>>(s1, row_ptr, col, agg, N_NODES);
            update_mfma<<<ugrid, 256, 0, stream>>>(
                s0, H_DIM, agg, w1h, w1l, wr1h, wr1l,
                s1, s1, N_NODES, leak_ptr);
        }
    }
}

// Round 5
// 1363.935 us; speedup vs baseline: 1.7275x; 1.6878x over previous
//
#include <hip/hip_runtime.h>
#include <math.h>

#define T_STEPS 8
#define N_NODES 20000
#define F_IN    128
#define H_DIM   256
#define E_EDGES 320000

typedef __attribute__((ext_vector_type(8))) short short8;
typedef __attribute__((ext_vector_type(4))) float f32x4;

__device__ __forceinline__ void split2(float v, unsigned short& h, unsigned short& l) {
    unsigned vi = __float_as_uint(v);
    h = (unsigned short)(vi >> 16);
    float hf = __uint_as_float(vi & 0xffff0000u);
    l = (unsigned short)(__float_as_uint(v - hf) >> 16);
}

// ---------------- CSR build ----------------

__global__ void count_kernel(const int* __restrict__ dst, int* __restrict__ counts, int E) {
    int e = blockIdx.x * blockDim.x + threadIdx.x;
    if (e < E) atomicAdd(&counts[dst[e]], 1);
}

__global__ void scan_kernel(const int* __restrict__ counts, int* __restrict__ row_ptr,
                            int* __restrict__ cursors, int n) {
    __shared__ int buf[1024];
    __shared__ int carry_s;
    int tid = threadIdx.x;
    if (tid == 0) carry_s = 0;
    __syncthreads();
    for (int base = 0; base < n; base += 1024) {
        int i = base + tid;
        int v = (i < n) ? counts[i] : 0;
        buf[tid] = v;
        __syncthreads();
        for (int off = 1; off < 1024; off <<= 1) {
            int t = (tid >= off) ? buf[tid - off] : 0;
            __syncthreads();
            buf[tid] += t;
            __syncthreads();
        }
        int incl = buf[tid];
        int carry = carry_s;
        if (i < n) {
            int ex = carry + incl - v;
            row_ptr[i] = ex;
            cursors[i] = ex;
        }
        __syncthreads();
        if (tid == 1023) carry_s = carry + incl;
        __syncthreads();
    }
    if (tid == 0) row_ptr[n] = carry_s;
}

__global__ void fill_kernel(const int* __restrict__ src, const int* __restrict__ dst,
                            int* __restrict__ cursors, int* __restrict__ col, int E) {
    int e = blockIdx.x * blockDim.x + threadIdx.x;
    if (e < E) {
        int d = dst[e];
        int p = atomicAdd(&cursors[d], 1);
        col[p] = src[e];
    }
}

// ---------------- weight fp32 -> MFMA-fragment-major bf16 hi/lo ----------------
// For mfma_f32_16x16x32_bf16, the B fragment for (n-tile rt, k-panel kp) is:
// lane holds B[rt*16 + (lane&15)][kp*32 + (lane>>4)*8 + j], j=0..7.
// Store frag-major: offset ((rt*KP32 + kp)*64 + lane)*8  -> one short8 per lane.

__global__ void cvt_frag(const float* __restrict__ W, int K,
                         unsigned short* __restrict__ fh, unsigned short* __restrict__ fl) {
    int g = blockIdx.x * 256 + threadIdx.x;
    int KP32 = K >> 5;
    int total = (H_DIM / 16) * KP32 * 64;
    if (g >= total) return;
    int lane = g & 63;
    int kp = (g >> 6) % KP32;
    int rt = g / (KP32 << 6);
    int r = rt * 16 + (lane & 15);
    int c = kp * 32 + (lane >> 4) * 8;
    const float* p = W + (size_t)r * K + c;
    short8 h, l;
    #pragma unroll
    for (int j = 0; j < 8; ++j) {
        unsigned short hh, ll;
        split2(p[j], hh, ll);
        h[j] = (short)hh; l[j] = (short)ll;
    }
    *(short8*)(fh + (size_t)g * 8) = h;
    *(short8*)(fl + (size_t)g * 8) = l;
}

// ---------------- merged gather: agg{0,1}[i,:] = sum_j s{0,1}[col[j],:] ----------------

__global__ __launch_bounds__(256) void gather2_kernel(
        const float* __restrict__ s0, const float* __restrict__ s1,
        const int* __restrict__ row_ptr, const int* __restrict__ col,
        float* __restrict__ agg0, float* __restrict__ agg1, int n) {
    const float* s  = blockIdx.y ? s1 : s0;
    float*       ag = blockIdx.y ? agg1 : agg0;
    int wv = threadIdx.x >> 6, lane = threadIdx.x & 63;
    int node = blockIdx.x * 4 + wv;
    if (node >= n) return;
    int beg = row_ptr[node], end = row_ptr[node + 1];
    const float4* s4 = (const float4*)s;
    float ax = 0.f, ay = 0.f, az = 0.f, aw = 0.f;
    float bx = 0.f, by = 0.f, bz = 0.f, bw = 0.f;
    int j = beg;
    for (; j + 1 < end; j += 2) {
        int c0 = col[j], c1 = col[j + 1];
        float4 v0 = s4[(size_t)c0 * 64 + lane];
        float4 v1 = s4[(size_t)c1 * 64 + lane];
        ax += v0.x; ay += v0.y; az += v0.z; aw += v0.w;
        bx += v1.x; by += v1.y; bz += v1.z; bw += v1.w;
    }
    if (j < end) {
        int c = col[j];
        float4 v = s4[(size_t)c * 64 + lane];
        ax += v.x; ay += v.y; az += v.z; aw += v.w;
    }
    float4 o;
    o.x = ax + bx; o.y = ay + by; o.z = az + bz; o.w = aw + bw;
    ((float4*)ag)[(size_t)node * 64 + lane] = o;
}

// ---------------- MFMA update: LDS-free, barrier-free register GEMM ----------------
// C[m,n] = sum_k A1[m,k] W1[n,k] (+ sum_k A2[m,k] W2[n,k])
// s_out = leak*tanh(C) + (1-leak)*s_old
// Block: 32 rows x 256 cols; 4 waves, each 32x64 (2 m-tiles x 4 n-tiles).
// A fp32 from global (32B/lane contiguous), split hi/lo in-register.
// B from frag-major bf16 hi/lo (16B/lane coalesced). 3-pass hi/lo MFMA.
// Grid = 625 blocks (20000 = 625*32, exact -> no guards). No LDS, no barriers.

__global__ __launch_bounds__(256) void update_mfma(
        const float* __restrict__ A1, int K1,
        const float* __restrict__ A2,
        const unsigned short* __restrict__ B1h, const unsigned short* __restrict__ B1l,
        const unsigned short* __restrict__ B2h, const unsigned short* __restrict__ B2l,
        const float* __restrict__ s_old, float* __restrict__ s_out,
        const float* __restrict__ leak_ptr) {
    const int tid = threadIdx.x;
    const int lane = tid & 63, w = tid >> 6;
    const int fr = lane & 15, fq = lane >> 4;
    const int m0 = blockIdx.x * 32;
    const int wn = w * 64;              // this wave's column block
    const int rtbase = wn >> 4;         // first n-tile index into frag-major weights

    f32x4 acc[2][4];
    #pragma unroll
    for (int mi = 0; mi < 2; ++mi)
        #pragma unroll
        for (int nt = 0; nt < 4; ++nt)
            acc[mi][nt] = (f32x4){0.f, 0.f, 0.f, 0.f};

    #pragma unroll 1
    for (int part = 0; part < 2; ++part) {
        const float* Af; int K;
        const unsigned short *Bh, *Bl;
        if (part == 0) { Af = A1; K = K1; Bh = B1h; Bl = B1l; }
        else {
            if (!A2) break;
            Af = A2; K = H_DIM; Bh = B2h; Bl = B2l;
        }
        const int KP32 = K >> 5;
        #pragma unroll 1
        for (int kp = 0; kp < KP32; ++kp) {
            // A fragments: lane reads 32 contiguous bytes of row m0+mi*16+fr
            short8 ah[2], al[2];
            #pragma unroll
            for (int mi = 0; mi < 2; ++mi) {
                const float* ap = Af + (size_t)(m0 + mi * 16 + fr) * K + kp * 32 + fq * 8;
                float4 v0 = *(const float4*)ap;
                float4 v1 = *(const float4*)(ap + 4);
                unsigned short h, l;
                split2(v0.x, h, l); ah[mi][0] = (short)h; al[mi][0] = (short)l;
                split2(v0.y, h, l); ah[mi][1] = (short)h; al[mi][1] = (short)l;
                split2(v0.z, h, l); ah[mi][2] = (short)h; al[mi][2] = (short)l;
                split2(v0.w, h, l); ah[mi][3] = (short)h; al[mi][3] = (short)l;
                split2(v1.x, h, l); ah[mi][4] = (short)h; al[mi][4] = (short)l;
                split2(v1.y, h, l); ah[mi][5] = (short)h; al[mi][5] = (short)l;
                split2(v1.z, h, l); ah[mi][6] = (short)h; al[mi][6] = (short)l;
                split2(v1.w, h, l); ah[mi][7] = (short)h; al[mi][7] = (short)l;
            }
            // B fragments: frag-major, 16B per lane
            short8 bh[4], bl[4];
            #pragma unroll
            for (int nt = 0; nt < 4; ++nt) {
                size_t off = ((size_t)((rtbase + nt) * KP32 + kp) * 64 + lane) * 8;
                bh[nt] = *(const short8*)(Bh + off);
                bl[nt] = *(const short8*)(Bl + off);
            }
            #pragma unroll
            for (int mi = 0; mi < 2; ++mi)
                #pragma unroll
                for (int nt = 0; nt < 4; ++nt) {
                    f32x4 c = acc[mi][nt];
                    c = __builtin_amdgcn_mfma_f32_16x16x32_bf16(ah[mi], bh[nt], c, 0, 0, 0);
                    c = __builtin_amdgcn_mfma_f32_16x16x32_bf16(al[mi], bh[nt], c, 0, 0, 0);
                    c = __builtin_amdgcn_mfma_f32_16x16x32_bf16(ah[mi], bl[nt], c, 0, 0, 0);
                    acc[mi][nt] = c;
                }
        }
    }

    // epilogue: C[m = m0+mi*16+fq*4+r][n = wn+nt*16+fr]
    const float leak = leak_ptr[0], il = 1.0f - leak;
    #pragma unroll
    for (int mi = 0; mi < 2; ++mi)
        #pragma unroll
        for (int r = 0; r < 4; ++r) {
            int m = m0 + mi * 16 + fq * 4 + r;
            #pragma unroll
            for (int nt = 0; nt < 4; ++nt) {
                int n = wn + nt * 16 + fr;
                size_t idx = (size_t)m * H_DIM + n;
                float old = s_old[idx];
                float pre = acc[mi][nt][r];
                float e = __expf(2.0f * pre);
                float th = 1.0f - 2.0f / (e + 1.0f);
                s_out[idx] = leak * th + il * old;
            }
        }
}

// ---------------- launch ----------------

extern "C" void kernel_launch(void* const* d_in, const int* in_sizes, int n_in,
                              void* d_out, int out_size, void* d_ws, size_t ws_size,
                              hipStream_t stream) {
    const float* x        = (const float*)d_in[0];
    const int*   edge     = (const int*)d_in[1];
    const float* w_in0    = (const float*)d_in[2];
    const float* w_rec0   = (const float*)d_in[3];
    const float* w_in1    = (const float*)d_in[4];
    const float* w_rec1   = (const float*)d_in[5];
    const float* leak_ptr = (const float*)d_in[6];

    const int* src = edge;
    const int* dst = edge + E_EDGES;

    float* s1 = (float*)d_out;

    char* ws = (char*)d_ws;
    size_t off = 0;
    auto alloc = [&](size_t bytes) -> char* {
        char* p = ws + off;
        off += (bytes + 255) & ~(size_t)255;
        return p;
    };
    const size_t state_bytes = (size_t)N_NODES * H_DIM * sizeof(float);
    float* s0   = (float*)alloc(state_bytes);
    float* agg0 = (float*)alloc(state_bytes);
    float* agg1 = (float*)alloc(state_bytes);
    unsigned short* w0h  = (unsigned short*)alloc(256 * 128 * 2);
    unsigned short* w0l  = (unsigned short*)alloc(256 * 128 * 2);
    unsigned short* wr0h = (unsigned short*)alloc(256 * 256 * 2);
    unsigned short* wr0l = (unsigned short*)alloc(256 * 256 * 2);
    unsigned short* w1h  = (unsigned short*)alloc(256 * 256 * 2);
    unsigned short* w1l  = (unsigned short*)alloc(256 * 256 * 2);
    unsigned short* wr1h = (unsigned short*)alloc(256 * 256 * 2);
    unsigned short* wr1l = (unsigned short*)alloc(256 * 256 * 2);
    int* row_ptr = (int*)alloc((N_NODES + 1) * sizeof(int));
    int* cursors = (int*)alloc(N_NODES * sizeof(int));
    int* counts  = (int*)alloc(N_NODES * sizeof(int));
    int* col     = (int*)alloc((size_t)E_EDGES * sizeof(int));

    hipMemsetAsync(s0, 0, state_bytes, stream);
    hipMemsetAsync(s1, 0, state_bytes, stream);
    hipMemsetAsync(counts, 0, N_NODES * sizeof(int), stream);

    // frag-major weight conversion (K=128: 4096 threads; K=256: 8192 threads)
    cvt_frag<<<16, 256, 0, stream>>>(w_in0, F_IN, w0h, w0l);
    cvt_frag<<<32, 256, 0, stream>>>(w_rec0, H_DIM, wr0h, wr0l);
    cvt_frag<<<32, 256, 0, stream>>>(w_in1, H_DIM, w1h, w1l);
    cvt_frag<<<32, 256, 0, stream>>>(w_rec1, H_DIM, wr1h, wr1l);

    count_kernel<<<(E_EDGES + 255) / 256, 256, 0, stream>>>(dst, counts, E_EDGES);
    scan_kernel<<<1, 1024, 0, stream>>>(counts, row_ptr, cursors, N_NODES);
    fill_kernel<<<(E_EDGES + 255) / 256, 256, 0, stream>>>(src, dst, cursors, col, E_EDGES);

    dim3 ggrid(N_NODES / 4, 2);          // 20000 = 5000*4 exact
    dim3 ugrid(N_NODES / 32);            // 20000 = 625*32 exact

    for (int t = 0; t < T_STEPS; ++t) {
        const float* xt = x + (size_t)t * N_NODES * F_IN;
        if (t == 0) {
            update_mfma<<<ugrid, 256, 0, stream>>>(
                xt, F_IN, nullptr, w0h, w0l, nullptr, nullptr,
                s0, s0, leak_ptr);
            update_mfma<<<ugrid, 256, 0, stream>>>(
                s0, H_DIM, nullptr, w1h, w1l, nullptr, nullptr,
                s1, s1, leak_ptr);
        } else {
            gather2_kernel<<<ggrid, 256, 0, stream>>>(s0, s1, row_ptr, col,
                                                      agg0, agg1, N_NODES);
            update_mfma<<<ugrid, 256, 0, stream>>>(
                xt, F_IN, agg0, w0h, w0l, wr0h, wr0l,
                s0, s0, leak_ptr);
            update_mfma<<<ugrid, 256, 0, stream>>>(
                s0, H_DIM, agg1, w1h, w1l, wr1h, wr1l,
                s1, s1, leak_ptr);
        }
    }
}

// Round 6
// 1265.313 us; speedup vs baseline: 1.8622x; 1.0779x over previous
//
#include <hip/hip_runtime.h>
#include <math.h>

#define T_STEPS 8
#define N_NODES 20000
#define F_IN    128
#define H_DIM   256
#define E_EDGES 320000

typedef __attribute__((ext_vector_type(8))) short short8;
typedef __attribute__((ext_vector_type(4))) float f32x4;

__device__ __forceinline__ void split2(float v, unsigned short& h, unsigned short& l) {
    unsigned vi = __float_as_uint(v);
    h = (unsigned short)(vi >> 16);
    float hf = __uint_as_float(vi & 0xffff0000u);
    l = (unsigned short)(__float_as_uint(v - hf) >> 16);
}

// ---------------- CSR build ----------------

__global__ void count_kernel(const int* __restrict__ dst, int* __restrict__ counts, int E) {
    int e = blockIdx.x * blockDim.x + threadIdx.x;
    if (e < E) atomicAdd(&counts[dst[e]], 1);
}

__global__ void scan_kernel(const int* __restrict__ counts, int* __restrict__ row_ptr,
                            int* __restrict__ cursors, int n) {
    __shared__ int buf[1024];
    __shared__ int carry_s;
    int tid = threadIdx.x;
    if (tid == 0) carry_s = 0;
    __syncthreads();
    for (int base = 0; base < n; base += 1024) {
        int i = base + tid;
        int v = (i < n) ? counts[i] : 0;
        buf[tid] = v;
        __syncthreads();
        for (int off = 1; off < 1024; off <<= 1) {
            int t = (tid >= off) ? buf[tid - off] : 0;
            __syncthreads();
            buf[tid] += t;
            __syncthreads();
        }
        int incl = buf[tid];
        int carry = carry_s;
        if (i < n) {
            int ex = carry + incl - v;
            row_ptr[i] = ex;
            cursors[i] = ex;
        }
        __syncthreads();
        if (tid == 1023) carry_s = carry + incl;
        __syncthreads();
    }
    if (tid == 0) row_ptr[n] = carry_s;
}

__global__ void fill_kernel(const int* __restrict__ src, const int* __restrict__ dst,
                            int* __restrict__ cursors, int* __restrict__ col, int E) {
    int e = blockIdx.x * blockDim.x + threadIdx.x;
    if (e < E) {
        int d = dst[e];
        int p = atomicAdd(&cursors[d], 1);
        col[p] = src[e];
    }
}

// ---------------- weight fp32 -> MFMA-fragment-major bf16 hi/lo ----------------
// lane holds B[rt*16 + (lane&15)][kp*32 + (lane>>4)*8 + j], j=0..7
// stored at ((rt*KP32 + kp)*64 + lane)*8 -> one 16B short8 per lane.

__global__ void cvt_frag(const float* __restrict__ W, int K,
                         unsigned short* __restrict__ fh, unsigned short* __restrict__ fl) {
    int g = blockIdx.x * 256 + threadIdx.x;
    int KP32 = K >> 5;
    int total = (H_DIM / 16) * KP32 * 64;
    if (g >= total) return;
    int lane = g & 63;
    int kp = (g >> 6) % KP32;
    int rt = g / (KP32 << 6);
    int r = rt * 16 + (lane & 15);
    int c = kp * 32 + (lane >> 4) * 8;
    const float* p = W + (size_t)r * K + c;
    short8 h, l;
    #pragma unroll
    for (int j = 0; j < 8; ++j) {
        unsigned short hh, ll;
        split2(p[j], hh, ll);
        h[j] = (short)hh; l[j] = (short)ll;
    }
    *(short8*)(fh + (size_t)g * 8) = h;
    *(short8*)(fl + (size_t)g * 8) = l;
}

// ---------------- fused gather + MFMA update ----------------
// Per block: 32 dst rows x 256 cols.
// Phase 1 (if do_gather): each wave gathers agg rows for 8 nodes into LDS
//   aggs[32][260] (pad-4 floats to spread banks), 4 edge-rows in flight.
// Phase 2: register GEMM, A1 dense fp32 from global, A2 from LDS aggs;
//   weights frag-major bf16 hi/lo; 3-pass split mfma_f32_16x16x32_bf16.
// s_new = leak*tanh(C) + (1-leak)*s_prev.  Ping-pong buffers outside: the
// gather reads s_prev while s_new is a different buffer -> no cross-block race.

__global__ __launch_bounds__(256) void fused_update(
        const float* __restrict__ A1, int K1,
        const float* __restrict__ s_prev,
        const unsigned short* __restrict__ B1h, const unsigned short* __restrict__ B1l,
        const unsigned short* __restrict__ B2h, const unsigned short* __restrict__ B2l,
        float* __restrict__ s_new,
        const int* __restrict__ row_ptr, const int* __restrict__ col,
        const float* __restrict__ leak_ptr, int do_gather) {
    __shared__ float aggs[32][260];
    const int tid = threadIdx.x;
    const int lane = tid & 63, w = tid >> 6;
    const int fr = lane & 15, fq = lane >> 4;
    const int m0 = blockIdx.x * 32;
    const int wn = w * 64;
    const int rtbase = w * 4;

    if (do_gather) {
        const float4* s4 = (const float4*)s_prev;
        #pragma unroll 1
        for (int i = 0; i < 8; ++i) {
            int r = w * 8 + i;
            int beg = row_ptr[m0 + r], end = row_ptr[m0 + r + 1];
            float x0 = 0.f, y0 = 0.f, z0 = 0.f, w0 = 0.f;
            float x1 = 0.f, y1 = 0.f, z1 = 0.f, w1 = 0.f;
            float x2 = 0.f, y2 = 0.f, z2 = 0.f, w2 = 0.f;
            float x3 = 0.f, y3 = 0.f, z3 = 0.f, w3 = 0.f;
            int j = beg;
            for (; j + 3 < end; j += 4) {
                int c0 = col[j], c1 = col[j + 1], c2 = col[j + 2], c3 = col[j + 3];
                float4 v0 = s4[(size_t)c0 * 64 + lane];
                float4 v1 = s4[(size_t)c1 * 64 + lane];
                float4 v2 = s4[(size_t)c2 * 64 + lane];
                float4 v3 = s4[(size_t)c3 * 64 + lane];
                x0 += v0.x; y0 += v0.y; z0 += v0.z; w0 += v0.w;
                x1 += v1.x; y1 += v1.y; z1 += v1.z; w1 += v1.w;
                x2 += v2.x; y2 += v2.y; z2 += v2.z; w2 += v2.w;
                x3 += v3.x; y3 += v3.y; z3 += v3.z; w3 += v3.w;
            }
            for (; j < end; ++j) {
                float4 v = s4[(size_t)col[j] * 64 + lane];
                x0 += v.x; y0 += v.y; z0 += v.z; w0 += v.w;
            }
            float4 t;
            t.x = (x0 + x1) + (x2 + x3);
            t.y = (y0 + y1) + (y2 + y3);
            t.z = (z0 + z1) + (z2 + z3);
            t.w = (w0 + w1) + (w2 + w3);
            *(float4*)&aggs[r][lane * 4] = t;
        }
        __syncthreads();
    }

    f32x4 acc[2][4];
    #pragma unroll
    for (int mi = 0; mi < 2; ++mi)
        #pragma unroll
        for (int nt = 0; nt < 4; ++nt)
            acc[mi][nt] = (f32x4){0.f, 0.f, 0.f, 0.f};

    // ---- part 1: dense A1 (fp32 global) ----
    {
        const int KP32 = K1 >> 5;
        #pragma unroll 1
        for (int kp = 0; kp < KP32; ++kp) {
            short8 ah[2], al[2];
            #pragma unroll
            for (int mi = 0; mi < 2; ++mi) {
                const float* ap = A1 + (size_t)(m0 + mi * 16 + fr) * K1 + kp * 32 + fq * 8;
                float4 v0 = *(const float4*)ap;
                float4 v1 = *(const float4*)(ap + 4);
                unsigned short h, l;
                split2(v0.x, h, l); ah[mi][0] = (short)h; al[mi][0] = (short)l;
                split2(v0.y, h, l); ah[mi][1] = (short)h; al[mi][1] = (short)l;
                split2(v0.z, h, l); ah[mi][2] = (short)h; al[mi][2] = (short)l;
                split2(v0.w, h, l); ah[mi][3] = (short)h; al[mi][3] = (short)l;
                split2(v1.x, h, l); ah[mi][4] = (short)h; al[mi][4] = (short)l;
                split2(v1.y, h, l); ah[mi][5] = (short)h; al[mi][5] = (short)l;
                split2(v1.z, h, l); ah[mi][6] = (short)h; al[mi][6] = (short)l;
                split2(v1.w, h, l); ah[mi][7] = (short)h; al[mi][7] = (short)l;
            }
            short8 bh[4], bl[4];
            #pragma unroll
            for (int nt = 0; nt < 4; ++nt) {
                size_t off = ((size_t)((rtbase + nt) * KP32 + kp) * 64 + lane) * 8;
                bh[nt] = *(const short8*)(B1h + off);
                bl[nt] = *(const short8*)(B1l + off);
            }
            #pragma unroll
            for (int mi = 0; mi < 2; ++mi)
                #pragma unroll
                for (int nt = 0; nt < 4; ++nt) {
                    f32x4 c = acc[mi][nt];
                    c = __builtin_amdgcn_mfma_f32_16x16x32_bf16(ah[mi], bh[nt], c, 0, 0, 0);
                    c = __builtin_amdgcn_mfma_f32_16x16x32_bf16(al[mi], bh[nt], c, 0, 0, 0);
                    c = __builtin_amdgcn_mfma_f32_16x16x32_bf16(ah[mi], bl[nt], c, 0, 0, 0);
                    acc[mi][nt] = c;
                }
        }
    }

    // ---- part 2: A2 = aggs (LDS) ----
    if (B2h) {
        #pragma unroll 1
        for (int kp = 0; kp < 8; ++kp) {
            short8 ah[2], al[2];
            #pragma unroll
            for (int mi = 0; mi < 2; ++mi) {
                const float* ap = &aggs[mi * 16 + fr][kp * 32 + fq * 8];
                float4 v0 = *(const float4*)ap;
                float4 v1 = *(const float4*)(ap + 4);
                unsigned short h, l;
                split2(v0.x, h, l); ah[mi][0] = (short)h; al[mi][0] = (short)l;
                split2(v0.y, h, l); ah[mi][1] = (short)h; al[mi][1] = (short)l;
                split2(v0.z, h, l); ah[mi][2] = (short)h; al[mi][2] = (short)l;
                split2(v0.w, h, l); ah[mi][3] = (short)h; al[mi][3] = (short)l;
                split2(v1.x, h, l); ah[mi][4] = (short)h; al[mi][4] = (short)l;
                split2(v1.y, h, l); ah[mi][5] = (short)h; al[mi][5] = (short)l;
                split2(v1.z, h, l); ah[mi][6] = (short)h; al[mi][6] = (short)l;
                split2(v1.w, h, l); ah[mi][7] = (short)h; al[mi][7] = (short)l;
            }
            short8 bh[4], bl[4];
            #pragma unroll
            for (int nt = 0; nt < 4; ++nt) {
                size_t off = ((size_t)((rtbase + nt) * 8 + kp) * 64 + lane) * 8;
                bh[nt] = *(const short8*)(B2h + off);
                bl[nt] = *(const short8*)(B2l + off);
            }
            #pragma unroll
            for (int mi = 0; mi < 2; ++mi)
                #pragma unroll
                for (int nt = 0; nt < 4; ++nt) {
                    f32x4 c = acc[mi][nt];
                    c = __builtin_amdgcn_mfma_f32_16x16x32_bf16(ah[mi], bh[nt], c, 0, 0, 0);
                    c = __builtin_amdgcn_mfma_f32_16x16x32_bf16(al[mi], bh[nt], c, 0, 0, 0);
                    c = __builtin_amdgcn_mfma_f32_16x16x32_bf16(ah[mi], bl[nt], c, 0, 0, 0);
                    acc[mi][nt] = c;
                }
        }
    }

    // ---- epilogue: C[m = m0+mi*16+fq*4+r][n = wn+nt*16+fr] ----
    const float leak = leak_ptr[0], il = 1.0f - leak;
    #pragma unroll
    for (int mi = 0; mi < 2; ++mi)
        #pragma unroll
        for (int r = 0; r < 4; ++r) {
            int m = m0 + mi * 16 + fq * 4 + r;
            #pragma unroll
            for (int nt = 0; nt < 4; ++nt) {
                int n = wn + nt * 16 + fr;
                size_t idx = (size_t)m * H_DIM + n;
                float old = s_prev[idx];
                float pre = acc[mi][nt][r];
                float e = __expf(2.0f * pre);
                float th = 1.0f - 2.0f / (e + 1.0f);
                s_new[idx] = leak * th + il * old;
            }
        }
}

// ---------------- launch ----------------

extern "C" void kernel_launch(void* const* d_in, const int* in_sizes, int n_in,
                              void* d_out, int out_size, void* d_ws, size_t ws_size,
                              hipStream_t stream) {
    const float* x        = (const float*)d_in[0];
    const int*   edge     = (const int*)d_in[1];
    const float* w_in0    = (const float*)d_in[2];
    const float* w_rec0   = (const float*)d_in[3];
    const float* w_in1    = (const float*)d_in[4];
    const float* w_rec1   = (const float*)d_in[5];
    const float* leak_ptr = (const float*)d_in[6];

    const int* src = edge;
    const int* dst = edge + E_EDGES;

    char* ws = (char*)d_ws;
    size_t off = 0;
    auto alloc = [&](size_t bytes) -> char* {
        char* p = ws + off;
        off += (bytes + 255) & ~(size_t)255;
        return p;
    };
    const size_t state_bytes = (size_t)N_NODES * H_DIM * sizeof(float);
    // ping-pong buffers; s1 buffer 0 is d_out (t=7 writes buffer (7+1)&1 = 0)
    float* s0b[2]; float* s1b[2];
    s0b[0] = (float*)alloc(state_bytes);
    s0b[1] = (float*)alloc(state_bytes);
    s1b[0] = (float*)d_out;
    s1b[1] = (float*)alloc(state_bytes);
    unsigned short* w0h  = (unsigned short*)alloc(256 * 128 * 2);
    unsigned short* w0l  = (unsigned short*)alloc(256 * 128 * 2);
    unsigned short* wr0h = (unsigned short*)alloc(256 * 256 * 2);
    unsigned short* wr0l = (unsigned short*)alloc(256 * 256 * 2);
    unsigned short* w1h  = (unsigned short*)alloc(256 * 256 * 2);
    unsigned short* w1l  = (unsigned short*)alloc(256 * 256 * 2);
    unsigned short* wr1h = (unsigned short*)alloc(256 * 256 * 2);
    unsigned short* wr1l = (unsigned short*)alloc(256 * 256 * 2);
    int* row_ptr = (int*)alloc((N_NODES + 1) * sizeof(int));
    int* cursors = (int*)alloc(N_NODES * sizeof(int));
    int* counts  = (int*)alloc(N_NODES * sizeof(int));
    int* col     = (int*)alloc((size_t)E_EDGES * sizeof(int));

    // t=0 reads buffer 0 as "previous" state -> must be zeros
    hipMemsetAsync(s0b[0], 0, state_bytes, stream);
    hipMemsetAsync(s1b[0], 0, state_bytes, stream);
    hipMemsetAsync(counts, 0, N_NODES * sizeof(int), stream);

    cvt_frag<<<16, 256, 0, stream>>>(w_in0, F_IN, w0h, w0l);
    cvt_frag<<<32, 256, 0, stream>>>(w_rec0, H_DIM, wr0h, wr0l);
    cvt_frag<<<32, 256, 0, stream>>>(w_in1, H_DIM, w1h, w1l);
    cvt_frag<<<32, 256, 0, stream>>>(w_rec1, H_DIM, wr1h, wr1l);

    count_kernel<<<(E_EDGES + 255) / 256, 256, 0, stream>>>(dst, counts, E_EDGES);
    scan_kernel<<<1, 1024, 0, stream>>>(counts, row_ptr, cursors, N_NODES);
    fill_kernel<<<(E_EDGES + 255) / 256, 256, 0, stream>>>(src, dst, cursors, col, E_EDGES);

    dim3 ugrid(N_NODES / 32);            // 20000 = 625*32 exact

    for (int t = 0; t < T_STEPS; ++t) {
        const float* xt = x + (size_t)t * N_NODES * F_IN;
        int rd = t & 1, wr = rd ^ 1;
        int dg = (t > 0) ? 1 : 0;
        fused_update<<<ugrid, 256, 0, stream>>>(
            xt, F_IN, s0b[rd],
            w0h, w0l, dg ? wr0h : nullptr, dg ? wr0l : nullptr,
            s0b[wr], row_ptr, col, leak_ptr, dg);
        fused_update<<<ugrid, 256, 0, stream>>>(
            s0b[wr], H_DIM, s1b[rd],
            w1h, w1l, dg ? wr1h : nullptr, dg ? wr1l : nullptr,
            s1b[wr], row_ptr, col, leak_ptr, dg);
    }
}